// Round 1
// 1164.889 us; speedup vs baseline: 1.5952x; 1.5952x over previous
//
#include <hip/hip_runtime.h>

// trajectory2seq: 2-layer GRU encoder (S=128) + attention decoder (6 steps)
// Round 2: occupancy-first restructure.
//   Both kernels: 1024 blocks x 512 thr; block owns 8 batch elems (bloc=tid&7),
//   work rows split across lanes (r=tid>>3), weights/tiles staged in LDS,
//   bijective XCD-chunked block swizzle for L2 locality.
//   enc_kernel: weights in LDS (padded rows, conflict-free b128 reads), x
//   double-buffered with register prefetch, 4 barriers/step, ~24 waves/CU.
//   dec_kernel: per-block enc tile [128][20][8] staged ONCE in LDS (84KB) ->
//   all 6 attention steps read LDS; shfl-based softmax/argmax reductions.
// ws layout unchanged: enc [128][20][8192] fp32 + hfin0/hfin1 [8192][20].

#define HN 20
#define DIN 64
#define NVOCAB 128
#define NB 8192
#define NS 128
#define NDEC 6

#define HID_OFF (NB * NDEC * NVOCAB)      // 6291456
#define ATTN_OFF (HID_OFF + 2 * NB * HN)  // 6619136

__device__ __forceinline__ float sigf(float x) {
    return 1.0f / (1.0f + __expf(-x));
}

__global__ __launch_bounds__(512)
void enc_kernel(const float* __restrict__ x,
                const float* __restrict__ Wih0, const float* __restrict__ Whh0,
                const float* __restrict__ bih0, const float* __restrict__ bhh0,
                const float* __restrict__ Wih1, const float* __restrict__ Whh1,
                const float* __restrict__ bih1, const float* __restrict__ bhh1,
                float* __restrict__ enc, float* __restrict__ hf0,
                float* __restrict__ hf1)
{
    // weight rows padded so 8 consecutive rows land on distinct bank groups
    __shared__ __align__(16) float W0[60][68];   // Wih0 [60][64]
    __shared__ __align__(16) float U0[60][28];   // Whh0 [60][20]
    __shared__ __align__(16) float W1[60][28];   // Wih1 [60][20]
    __shared__ __align__(16) float U1[60][28];   // Whh1 [60][20]
    __shared__ float bi0[60], bh0[60], bi1[60], bh1[60];
    __shared__ __align__(16) float xs[2][8][68]; // double-buffered x tile
    __shared__ __align__(16) float h0s[8][24];
    __shared__ __align__(16) float h1s[8][24];
    __shared__ float gs[8][80];                  // [r,z | inn | hn]

    const int tid  = threadIdx.x;
    const int bloc = tid & 7;        // batch elem within block
    const int r    = tid >> 3;       // gate row 0..63 (rows >=60 idle in gates)
    const int sb   = tid >> 6;       // staging: batch lane 0..7
    const int si   = tid & 63;       // staging: input feature 0..63
    const int bid  = (int)blockIdx.x;
    const int gblk = (bid & 7) * 128 + (bid >> 3);  // XCD-chunked, bijective (1024%8==0)
    const int b0   = gblk * 8;

    for (int idx = tid; idx < 60 * 64; idx += 512)
        W0[idx >> 6][idx & 63] = Wih0[idx];
    for (int idx = tid; idx < 60 * 20; idx += 512) {
        int rr = idx / 20, ii = idx % 20;
        U0[rr][ii] = Whh0[idx];
        W1[rr][ii] = Wih1[idx];
        U1[rr][ii] = Whh1[idx];
    }
    if (tid < 60) {
        bi0[tid] = bih0[tid]; bh0[tid] = bhh0[tid];
        bi1[tid] = bih1[tid]; bh1[tid] = bhh1[tid];
    }
    for (int idx = tid; idx < 8 * 24; idx += 512) {
        (&h0s[0][0])[idx] = 0.0f;
        (&h1s[0][0])[idx] = 0.0f;
    }
    xs[0][sb][si] = x[(b0 + sb) * (NS * DIN) + si];   // t = 0
    __syncthreads();

    int cur = 0;
    for (int t = 0; t < NS; ++t) {
        // issue next-step x load early; written to LDS after phase-A barrier
        float pf = 0.0f;
        if (t + 1 < NS)
            pf = x[((b0 + sb) * NS + t + 1) * DIN + si];

        // ---- phase A: layer-0 gate pre-activations ----
        if (r < 60) {
            float ax = bi0[r], ah = bh0[r];
            #pragma unroll
            for (int i = 0; i < DIN; ++i) ax += W0[r][i] * xs[cur][bloc][i];
            #pragma unroll
            for (int i = 0; i < HN; ++i)  ah += U0[r][i] * h0s[bloc][i];
            if (r < 40) gs[bloc][r] = ax + ah;
            else { gs[bloc][r] = ax; gs[bloc][r + 20] = ah; }  // inn, hn split
        }
        __syncthreads();

        // ---- phase B: h0 update (+ write prefetched x tile) ----
        xs[cur ^ 1][sb][si] = pf;   // xs[cur^1] last read 3 barriers ago
        if (r < HN) {
            float rr = sigf(gs[bloc][r]);
            float z  = sigf(gs[bloc][20 + r]);
            float n  = tanhf(gs[bloc][40 + r] + rr * gs[bloc][60 + r]);
            float hnew = (1.0f - z) * n + z * h0s[bloc][r];
            h0s[bloc][r] = hnew;
            if (t == NS - 1) hf0[(b0 + bloc) * HN + r] = hnew;
        }
        __syncthreads();

        // ---- phase C: layer-1 gate pre-activations ----
        if (r < 60) {
            float ax = bi1[r], ah = bh1[r];
            #pragma unroll
            for (int i = 0; i < HN; ++i) ax += W1[r][i] * h0s[bloc][i];
            #pragma unroll
            for (int i = 0; i < HN; ++i) ah += U1[r][i] * h1s[bloc][i];
            if (r < 40) gs[bloc][r] = ax + ah;
            else { gs[bloc][r] = ax; gs[bloc][r + 20] = ah; }
        }
        __syncthreads();

        // ---- phase D: h1 update + enc write ----
        if (r < HN) {
            float rr = sigf(gs[bloc][r]);
            float z  = sigf(gs[bloc][20 + r]);
            float n  = tanhf(gs[bloc][40 + r] + rr * gs[bloc][60 + r]);
            float hnew = (1.0f - z) * n + z * h1s[bloc][r];
            h1s[bloc][r] = hnew;
            enc[(t * HN + r) * NB + b0 + bloc] = hnew;   // [t][k][b]
            if (t == NS - 1) hf1[(b0 + bloc) * HN + r] = hnew;
        }
        __syncthreads();
        cur ^= 1;
    }
}

__global__ __launch_bounds__(512)
void dec_kernel(const float* __restrict__ dWih0, const float* __restrict__ dWhh0,
                const float* __restrict__ dbih0, const float* __restrict__ dbhh0,
                const float* __restrict__ dWih1, const float* __restrict__ dWhh1,
                const float* __restrict__ dbih1, const float* __restrict__ dbhh1,
                const float* __restrict__ emb,  const float* __restrict__ qW,
                const float* __restrict__ qb,   const float* __restrict__ combW,
                const float* __restrict__ combb, const float* __restrict__ outW,
                const float* __restrict__ outb,
                const float* __restrict__ enc, const float* __restrict__ hf0,
                const float* __restrict__ hf1, float* __restrict__ out)
{
    __shared__ __align__(16) float el[NS * 164];  // enc tile [t][k][b]: t*164+k*8+b (pad 160->164)
    __shared__ float ssb[NS * 9];                 // scores/e / logits [t|v][bloc], pad 9
    __shared__ float hd0[8][24], hd1[8][24];
    __shared__ float gsd[8][80];
    __shared__ float qs[8][24];
    __shared__ float combp[8][24];                // comb accumulator (buf part, then +ctx)
    __shared__ float cxp[2][20][8];               // context partials per t-half
    __shared__ float pm[8][8];                    // per-wave reduction partials
    __shared__ int   pi[8][8];
    __shared__ float Ms[8], Sv[8];
    __shared__ int   toks[8];

    const int tid  = threadIdx.x;
    const int bloc = tid & 7;
    const int r    = tid >> 3;       // 0..63
    const int wv   = tid >> 6;       // wave 0..7
    const int bid  = (int)blockIdx.x;
    const int gblk = (bid & 7) * 128 + (bid >> 3);
    const int b0   = gblk * 8;

    for (int idx = tid; idx < 8 * HN; idx += 512) {
        int bb = idx & 7, k = idx >> 3;
        hd0[bb][k] = hf0[(b0 + bb) * HN + k];
        hd1[bb][k] = hf1[(b0 + bb) * HN + k];
    }
    if (tid < 8) toks[tid] = 0;
    // stage enc tile once: 6 steps of attention then read LDS only
    for (int idx = tid; idx < NS * HN * 2; idx += 512) {   // 10 float4 per thread
        int tk = idx >> 1, q = idx & 1;
        int t = tk / HN, k = tk % HN;
        float4 v = *(const float4*)(enc + (size_t)tk * NB + b0 + 4 * q);
        *(float4*)(&el[t * 164 + k * 8 + 4 * q]) = v;
    }
    __syncthreads();

    for (int s = 0; s < NDEC; ++s) {
        // ---- GRU layer 0 (embedding read fused: 8 rows/wave from L1-hot emb) ----
        if (r < 60) {
            const float* er = emb + toks[bloc] * HN;
            float ax = dbih0[r], ah = dbhh0[r];
            #pragma unroll
            for (int i = 0; i < HN; ++i) {
                ax += dWih0[r * HN + i] * er[i];
                ah += dWhh0[r * HN + i] * hd0[bloc][i];
            }
            if (r < 40) gsd[bloc][r] = ax + ah;
            else { gsd[bloc][r] = ax; gsd[bloc][r + 20] = ah; }
        }
        __syncthreads();
        if (r < HN) {
            float rr = sigf(gsd[bloc][r]);
            float z  = sigf(gsd[bloc][20 + r]);
            float n  = tanhf(gsd[bloc][40 + r] + rr * gsd[bloc][60 + r]);
            hd0[bloc][r] = (1.0f - z) * n + z * hd0[bloc][r];
        }
        __syncthreads();
        // ---- GRU layer 1 ----
        if (r < 60) {
            float ax = dbih1[r], ah = dbhh1[r];
            #pragma unroll
            for (int i = 0; i < HN; ++i) {
                ax += dWih1[r * HN + i] * hd0[bloc][i];
                ah += dWhh1[r * HN + i] * hd1[bloc][i];
            }
            if (r < 40) gsd[bloc][r] = ax + ah;
            else { gsd[bloc][r] = ax; gsd[bloc][r + 20] = ah; }
        }
        __syncthreads();
        if (r < HN) {
            float rr = sigf(gsd[bloc][r]);
            float z  = sigf(gsd[bloc][20 + r]);
            float n  = tanhf(gsd[bloc][40 + r] + rr * gsd[bloc][60 + r]);
            hd1[bloc][r] = (1.0f - z) * n + z * hd1[bloc][r];
        }
        __syncthreads();
        // ---- query (r<20) + comb buf-part (20<=r<40, independent of ctx) ----
        if (r < HN) {
            float a = qb[r];
            #pragma unroll
            for (int i = 0; i < HN; ++i) a += qW[r * HN + i] * hd1[bloc][i];
            qs[bloc][r] = a;
        } else if (r < 2 * HN) {
            int k = r - HN;
            float a = combb[k];
            #pragma unroll
            for (int i = 0; i < HN; ++i) a += combW[k * 2 * HN + i] * hd1[bloc][i];
            combp[bloc][k] = a;
        }
        __syncthreads();
        // ---- scores: thread owns t=r and t=64+r; wave-partial max via shfl ----
        float s0 = 0.0f, s1 = 0.0f;
        #pragma unroll
        for (int k = 0; k < HN; ++k) {
            float q = qs[bloc][k];
            s0 += q * el[r * 164 + k * 8 + bloc];
            s1 += q * el[(64 + r) * 164 + k * 8 + bloc];
        }
        {
            float m = fmaxf(s0, s1);
            m = fmaxf(m, __shfl_xor(m, 8));
            m = fmaxf(m, __shfl_xor(m, 16));
            m = fmaxf(m, __shfl_xor(m, 32));
            if (((tid >> 3) & 7) == 0) pm[wv][bloc] = m;
        }
        __syncthreads();
        if (tid < 8) {
            float m = pm[0][tid];
            #pragma unroll
            for (int w2 = 1; w2 < 8; ++w2) m = fmaxf(m, pm[w2][tid]);
            Ms[tid] = m;
        }
        __syncthreads();
        // ---- exp + wave-partial sum ----
        float e0 = __expf(s0 - Ms[bloc]);
        float e1 = __expf(s1 - Ms[bloc]);
        ssb[r * 9 + bloc] = e0;
        ssb[(64 + r) * 9 + bloc] = e1;
        {
            float sm = e0 + e1;
            sm += __shfl_xor(sm, 8);
            sm += __shfl_xor(sm, 16);
            sm += __shfl_xor(sm, 32);
            if (((tid >> 3) & 7) == 0) pm[wv][bloc] = sm;
        }
        __syncthreads();
        if (tid < 8) {
            float sm = pm[0][tid];
            #pragma unroll
            for (int w2 = 1; w2 < 8; ++w2) sm += pm[w2][tid];
            Sv[tid] = 1.0f / sm;
        }
        __syncthreads();
        // ---- attn write (coalesced v-remap) + context partials (raw e, scale by Sv) ----
        {
            int vb = wv, vt = tid & 63;
            float inv = Sv[vb];
            size_t abase = (size_t)ATTN_OFF + (size_t)s * NB * NS + (size_t)(b0 + vb) * NS;
            out[abase + vt]      = ssb[vt * 9 + vb] * inv;
            out[abase + vt + 64] = ssb[(vt + 64) * 9 + vb] * inv;
        }
        if (r < 2 * HN) {
            int k  = (r < HN) ? r : r - HN;
            int tb = (r < HN) ? 0 : 64;
            float acc = 0.0f;
            for (int u = 0; u < 64; ++u)
                acc += ssb[(tb + u) * 9 + bloc] * el[(tb + u) * 164 + k * 8 + bloc];
            cxp[(r < HN) ? 0 : 1][k][bloc] = acc * Sv[bloc];
        }
        __syncthreads();
        // ---- comb += ctx part ----
        if (r < HN) {
            float a = combp[bloc][r];
            #pragma unroll
            for (int i = 0; i < HN; ++i)
                a += combW[r * 2 * HN + HN + i] * (cxp[0][i][bloc] + cxp[1][i][bloc]);
            combp[bloc][r] = a;
        }
        __syncthreads();
        // ---- logits (thread owns v=r, v=64+r) + first-index argmax ----
        {
            float lg0 = outb[r], lg1 = outb[64 + r];
            #pragma unroll
            for (int k = 0; k < HN; ++k) {
                float c = combp[bloc][k];
                lg0 += outW[r * HN + k] * c;
                lg1 += outW[(64 + r) * HN + k] * c;
            }
            ssb[r * 9 + bloc] = lg0;
            ssb[(64 + r) * 9 + bloc] = lg1;
            float bv = lg0; int bi2 = r;
            if (lg1 > bv) { bv = lg1; bi2 = 64 + r; }
            #pragma unroll
            for (int d = 8; d <= 32; d <<= 1) {
                float ov = __shfl_xor(bv, d);
                int   oi = __shfl_xor(bi2, d);
                if (ov > bv || (ov == bv && oi < bi2)) { bv = ov; bi2 = oi; }
            }
            if (((tid >> 3) & 7) == 0) { pm[wv][bloc] = bv; pi[wv][bloc] = bi2; }
        }
        __syncthreads();
        // ---- logits write (coalesced) + final argmax -> next token ----
        {
            int vb = wv, vt = tid & 63;
            size_t lbase = (size_t)(b0 + vb) * (NDEC * NVOCAB) + (size_t)s * NVOCAB;
            out[lbase + vt]      = ssb[vt * 9 + vb];
            out[lbase + vt + 64] = ssb[(vt + 64) * 9 + vb];
        }
        if (tid < 8) {
            float bv = pm[0][tid]; int bi2 = pi[0][tid];
            #pragma unroll
            for (int w2 = 1; w2 < 8; ++w2) {
                float ov = pm[w2][tid]; int oi = pi[w2][tid];
                if (ov > bv || (ov == bv && oi < bi2)) { bv = ov; bi2 = oi; }
            }
            toks[tid] = bi2;
        }
        __syncthreads();
    }

    // ---- final hidden state [2][B][H] ----
    for (int idx = tid; idx < 8 * HN; idx += 512) {
        int bb = idx & 7, k = idx >> 3;
        out[HID_OFF + (b0 + bb) * HN + k] = hd0[bb][k];
        out[HID_OFF + NB * HN + (b0 + bb) * HN + k] = hd1[bb][k];
    }
}

extern "C" void kernel_launch(void* const* d_in, const int* in_sizes, int n_in,
                              void* d_out, int out_size, void* d_ws, size_t ws_size,
                              hipStream_t stream)
{
    const float* x        = (const float*)d_in[0];
    const float* eWih0    = (const float*)d_in[1];
    const float* eWhh0    = (const float*)d_in[2];
    const float* ebih0    = (const float*)d_in[3];
    const float* ebhh0    = (const float*)d_in[4];
    const float* eWih1    = (const float*)d_in[5];
    const float* eWhh1    = (const float*)d_in[6];
    const float* ebih1    = (const float*)d_in[7];
    const float* ebhh1    = (const float*)d_in[8];
    const float* dWih0    = (const float*)d_in[9];
    const float* dWhh0    = (const float*)d_in[10];
    const float* dbih0    = (const float*)d_in[11];
    const float* dbhh0    = (const float*)d_in[12];
    const float* dWih1    = (const float*)d_in[13];
    const float* dWhh1    = (const float*)d_in[14];
    const float* dbih1    = (const float*)d_in[15];
    const float* dbhh1    = (const float*)d_in[16];
    const float* emb      = (const float*)d_in[17];
    const float* qW       = (const float*)d_in[18];
    const float* qb       = (const float*)d_in[19];
    const float* combW    = (const float*)d_in[20];
    const float* combb    = (const float*)d_in[21];
    const float* outW     = (const float*)d_in[22];
    const float* outb     = (const float*)d_in[23];

    // workspace: enc [NS][HN][NB] + hfin0 [NB][HN] + hfin1 [NB][HN]
    const size_t need = ((size_t)NS * HN * NB + 2 * (size_t)NB * HN) * sizeof(float);
    if (ws_size < need) return;

    float* ws  = (float*)d_ws;
    float* enc = ws;
    float* hf0 = ws + (size_t)NS * HN * NB;
    float* hf1 = hf0 + (size_t)NB * HN;

    enc_kernel<<<1024, 512, 0, stream>>>(x, eWih0, eWhh0, ebih0, ebhh0,
                                         eWih1, eWhh1, ebih1, ebhh1,
                                         enc, hf0, hf1);
    dec_kernel<<<1024, 512, 0, stream>>>(dWih0, dWhh0, dbih0, dbhh0,
                                         dWih1, dWhh1, dbih1, dbhh1,
                                         emb, qW, qb, combW, combb, outW, outb,
                                         enc, hf0, hf1, (float*)d_out);
}

// Round 2
// 1092.251 us; speedup vs baseline: 1.7013x; 1.0665x over previous
//
#include <hip/hip_runtime.h>

// trajectory2seq: 2-layer GRU encoder (S=128) + attention decoder (6 steps)
// Round 3: barrier/occupancy attack.
//   enc: LDS cut to 40512B -> 4 blocks/CU, all 1024 blocks co-resident (no
//        tail); L1 pipelined one step behind L0 -> 2 barriers/step (was 4);
//        gate buffers transposed [80][8] -> 2-way max bank aliasing (free).
//        Weight pads 28->20 (rows stay 16B-aligned; broadcast reads are
//        conflict-free: 20r mod 32 distinct over 8 consecutive r).
//   dec: 1024 thr (16 waves); ALL weights (GRU/q/comb/out/emb, ~55KB) staged
//        in LDS once (6x reuse; they exceed the 32KB L1 and were thrashing);
//        scores 1 t/thread, logits 1 v/thread, context 4-way t-split.
// ws layout unchanged: enc [128][20][8192] fp32 + hfin0/hfin1 [8192][20].

#define HN 20
#define DIN 64
#define NVOCAB 128
#define NB 8192
#define NS 128
#define NDEC 6

#define HID_OFF (NB * NDEC * NVOCAB)      // 6291456
#define ATTN_OFF (HID_OFF + 2 * NB * HN)  // 6619136

__device__ __forceinline__ float sigf(float x) {
    return 1.0f / (1.0f + __expf(-x));
}

__global__ __launch_bounds__(512, 8)
void enc_kernel(const float* __restrict__ x,
                const float* __restrict__ Wih0, const float* __restrict__ Whh0,
                const float* __restrict__ bih0, const float* __restrict__ bhh0,
                const float* __restrict__ Wih1, const float* __restrict__ Whh1,
                const float* __restrict__ bih1, const float* __restrict__ bhh1,
                float* __restrict__ enc, float* __restrict__ hf0,
                float* __restrict__ hf1)
{
    // LDS budget 40512B -> 4 blocks/CU (4*40960 granule = 160KiB exactly)
    __shared__ __align__(16) float W0[60][68];   // 16320 (68: 4r mod 32 distinct)
    __shared__ __align__(16) float U0[60][20];   // 4800
    __shared__ __align__(16) float W1[60][20];   // 4800
    __shared__ __align__(16) float U1[60][20];   // 4800
    __shared__ float bi0[60], bh0[60], bi1[60], bh1[60];  // 960
    __shared__ __align__(16) float xs[8][68];    // 2176 (single buffer)
    __shared__ __align__(16) float h0s[8][24];   // 768
    __shared__ __align__(16) float h1s[8][24];   // 768
    __shared__ float gA[80][8];                  // 2560 L0 gates(t):   2-way max
    __shared__ float gB[80][8];                  // 2560 L1 gates(t-1): 2-way max

    const int tid  = threadIdx.x;
    const int bloc = tid & 7;        // batch elem within block
    const int r    = tid >> 3;       // gate row 0..63
    const int sb   = tid >> 6;       // staging: batch lane 0..7 (wave-uniform)
    const int si   = tid & 63;       // staging: input feature 0..63
    const int bid  = (int)blockIdx.x;
    const int gblk = (bid & 7) * 128 + (bid >> 3);  // XCD-chunked, bijective
    const int b0   = gblk * 8;

    for (int idx = tid; idx < 60 * 64; idx += 512)
        W0[idx >> 6][idx & 63] = Wih0[idx];
    for (int idx = tid; idx < 60 * 20; idx += 512) {
        (&U0[0][0])[idx] = Whh0[idx];
        (&W1[0][0])[idx] = Wih1[idx];
        (&U1[0][0])[idx] = Whh1[idx];
    }
    if (tid < 60) {
        bi0[tid] = bih0[tid]; bh0[tid] = bhh0[tid];
        bi1[tid] = bih1[tid]; bh1[tid] = bhh1[tid];
    }
    for (int idx = tid; idx < 8 * 24; idx += 512) {
        (&h0s[0][0])[idx] = 0.0f;
        (&h1s[0][0])[idx] = 0.0f;
    }
    xs[sb][si] = x[(b0 + sb) * (NS * DIN) + si];   // t = 0
    __syncthreads();

    // software-pipelined: iter i computes gates0(t=i) and gates1(t=i-1)
    for (int i = 0; i <= NS; ++i) {
        // prefetch x[t=i+1] (consumed in update phase, after the barrier)
        float pf = 0.0f;
        const bool havepf = (i <= NS - 2);
        if (havepf)
            pf = x[((b0 + sb) * NS + i + 1) * DIN + si];

        // ---- phase G: both gate sets (read-only on xs/h0s/h1s) ----
        const bool g0 = (i < NS)  && (r < 60);
        const bool g1 = (i >= 1)  && (r < 60);
        if (g0) {
            float ax = bi0[r];
            #pragma unroll
            for (int q = 0; q < 16; ++q) {
                float4 wv = *(const float4*)(&W0[r][4 * q]);
                float4 xv = *(const float4*)(&xs[bloc][4 * q]);
                ax += wv.x * xv.x + wv.y * xv.y + wv.z * xv.z + wv.w * xv.w;
            }
            float ah = bh0[r];
            #pragma unroll
            for (int q = 0; q < 5; ++q) {
                float4 uv = *(const float4*)(&U0[r][4 * q]);
                float4 hv = *(const float4*)(&h0s[bloc][4 * q]);
                ah += uv.x * hv.x + uv.y * hv.y + uv.z * hv.z + uv.w * hv.w;
            }
            if (r < 40) gA[r][bloc] = ax + ah;
            else { gA[r][bloc] = ax; gA[r + 20][bloc] = ah; }  // inn | hn
        }
        if (g1) {
            float bx = bi1[r];
            #pragma unroll
            for (int q = 0; q < 5; ++q) {
                float4 wv = *(const float4*)(&W1[r][4 * q]);
                float4 hv = *(const float4*)(&h0s[bloc][4 * q]);
                bx += wv.x * hv.x + wv.y * hv.y + wv.z * hv.z + wv.w * hv.w;
            }
            float bh = bh1[r];
            #pragma unroll
            for (int q = 0; q < 5; ++q) {
                float4 uv = *(const float4*)(&U1[r][4 * q]);
                float4 hv = *(const float4*)(&h1s[bloc][4 * q]);
                bh += uv.x * hv.x + uv.y * hv.y + uv.z * hv.z + uv.w * hv.w;
            }
            if (r < 40) gB[r][bloc] = bx + bh;
            else { gB[r][bloc] = bx; gB[r + 20][bloc] = bh; }
        }
        __syncthreads();

        // ---- phase U: write prefetched x; update h0(i) and h1(i-1) ----
        if (havepf) xs[sb][si] = pf;
        if (r < HN) {
            if (i < NS) {
                float rr = sigf(gA[r][bloc]);
                float z  = sigf(gA[20 + r][bloc]);
                float n  = tanhf(gA[40 + r][bloc] + rr * gA[60 + r][bloc]);
                float hnew = (1.0f - z) * n + z * h0s[bloc][r];
                h0s[bloc][r] = hnew;
                if (i == NS - 1) hf0[(b0 + bloc) * HN + r] = hnew;
            }
            if (i >= 1) {
                int t1 = i - 1;
                float rr = sigf(gB[r][bloc]);
                float z  = sigf(gB[20 + r][bloc]);
                float n  = tanhf(gB[40 + r][bloc] + rr * gB[60 + r][bloc]);
                float hnew = (1.0f - z) * n + z * h1s[bloc][r];
                h1s[bloc][r] = hnew;
                enc[(t1 * HN + r) * NB + b0 + bloc] = hnew;   // [t][k][b]
                if (t1 == NS - 1) hf1[(b0 + bloc) * HN + r] = hnew;
            }
        }
        __syncthreads();
    }
}

__global__ __launch_bounds__(1024, 4)
void dec_kernel(const float* __restrict__ dWih0, const float* __restrict__ dWhh0,
                const float* __restrict__ dbih0, const float* __restrict__ dbhh0,
                const float* __restrict__ dWih1, const float* __restrict__ dWhh1,
                const float* __restrict__ dbih1, const float* __restrict__ dbhh1,
                const float* __restrict__ emb,  const float* __restrict__ qW,
                const float* __restrict__ qb,   const float* __restrict__ combW,
                const float* __restrict__ combb, const float* __restrict__ outW,
                const float* __restrict__ outb,
                const float* __restrict__ enc, const float* __restrict__ hf0,
                const float* __restrict__ hf1, float* __restrict__ out)
{
    __shared__ __align__(16) float el[NS * 164]; // 83968 enc tile [t][k][8]
    __shared__ float ssb[NS * 9];                // 4608 scores/e/logits [t|v][bloc]
    __shared__ __align__(16) float Wih0s[60][20], Whh0s[60][20];  // 9600
    __shared__ __align__(16) float Wih1s[60][20], Whh1s[60][20];  // 9600
    __shared__ __align__(16) float qWs[20][20];   // 1600
    __shared__ __align__(16) float combWs[20][40];// 3200
    __shared__ __align__(16) float outWs[128][20];// 10240
    __shared__ __align__(16) float embs[128][20]; // 10240
    __shared__ float bi0s[60], bh0s[60], bi1s[60], bh1s[60];      // 960
    __shared__ float qbs[20], cbbs[20], outbs[128];               // 672
    __shared__ float hd0[8][24], hd1[8][24];     // 1536
    __shared__ float gsd[80][8];                 // 2560 (transposed, 2-way max)
    __shared__ float qs[8][24];                  // 768
    __shared__ float combp[8][24];               // 768
    __shared__ float cxp[4][20][8];              // 2560 context partials
    __shared__ float pm[16][8];                  // 512 per-wave reduction
    __shared__ int   pix[16][8];                 // 512
    __shared__ float Ms[8], Sv[8];               // 64
    __shared__ int   toks[8];                    // 32

    const int tid  = threadIdx.x;
    const int bloc = tid & 7;
    const int r    = tid >> 3;       // 0..127
    const int wv   = tid >> 6;       // wave 0..15
    const int bid  = (int)blockIdx.x;
    const int gblk = (bid & 7) * 128 + (bid >> 3);
    const int b0   = gblk * 8;

    // ---- stage all weights (6x reuse; ~55KB working set thrashed L1) ----
    for (int idx = tid; idx < 60 * 20; idx += 1024) {
        (&Wih0s[0][0])[idx] = dWih0[idx];
        (&Whh0s[0][0])[idx] = dWhh0[idx];
        (&Wih1s[0][0])[idx] = dWih1[idx];
        (&Whh1s[0][0])[idx] = dWhh1[idx];
    }
    for (int idx = tid; idx < 400; idx += 1024) (&qWs[0][0])[idx] = qW[idx];
    for (int idx = tid; idx < 800; idx += 1024) (&combWs[0][0])[idx] = combW[idx];
    for (int idx = tid; idx < 2560; idx += 1024) {
        (&outWs[0][0])[idx] = outW[idx];
        (&embs[0][0])[idx]  = emb[idx];
    }
    if (tid < 60) {
        bi0s[tid] = dbih0[tid]; bh0s[tid] = dbhh0[tid];
        bi1s[tid] = dbih1[tid]; bh1s[tid] = dbhh1[tid];
    }
    if (tid < 20) { qbs[tid] = qb[tid]; cbbs[tid] = combb[tid]; }
    if (tid < 128) outbs[tid] = outb[tid];
    for (int idx = tid; idx < 8 * HN; idx += 1024) {
        int bb = idx & 7, k = idx >> 3;
        hd0[bb][k] = hf0[(b0 + bb) * HN + k];
        hd1[bb][k] = hf1[(b0 + bb) * HN + k];
    }
    if (tid < 8) toks[tid] = 0;
    // stage enc tile once (all 6 attention steps read LDS)
    for (int idx = tid; idx < NS * HN * 2; idx += 1024) {
        int tk = idx >> 1, q = idx & 1;
        int t = tk / HN, k = tk % HN;
        float4 v = *(const float4*)(enc + (size_t)tk * NB + b0 + 4 * q);
        *(float4*)(&el[t * 164 + k * 8 + 4 * q]) = v;
    }
    __syncthreads();

    for (int s = 0; s < NDEC; ++s) {
        // ---- GRU layer 0 ----
        if (r < 60) {
            const float* er = &embs[toks[bloc]][0];
            float ax = bi0s[r], ah = bh0s[r];
            #pragma unroll
            for (int i = 0; i < HN; ++i) {
                ax += Wih0s[r][i] * er[i];
                ah += Whh0s[r][i] * hd0[bloc][i];
            }
            if (r < 40) gsd[r][bloc] = ax + ah;
            else { gsd[r][bloc] = ax; gsd[r + 20][bloc] = ah; }
        }
        __syncthreads();
        if (r < HN) {
            float rr = sigf(gsd[r][bloc]);
            float z  = sigf(gsd[20 + r][bloc]);
            float n  = tanhf(gsd[40 + r][bloc] + rr * gsd[60 + r][bloc]);
            hd0[bloc][r] = (1.0f - z) * n + z * hd0[bloc][r];
        }
        __syncthreads();
        // ---- GRU layer 1 ----
        if (r < 60) {
            float ax = bi1s[r], ah = bh1s[r];
            #pragma unroll
            for (int i = 0; i < HN; ++i) {
                ax += Wih1s[r][i] * hd0[bloc][i];
                ah += Whh1s[r][i] * hd1[bloc][i];
            }
            if (r < 40) gsd[r][bloc] = ax + ah;
            else { gsd[r][bloc] = ax; gsd[r + 20][bloc] = ah; }
        }
        __syncthreads();
        if (r < HN) {
            float rr = sigf(gsd[r][bloc]);
            float z  = sigf(gsd[20 + r][bloc]);
            float n  = tanhf(gsd[40 + r][bloc] + rr * gsd[60 + r][bloc]);
            hd1[bloc][r] = (1.0f - z) * n + z * hd1[bloc][r];
        }
        __syncthreads();
        // ---- query (r<20) + comb buf-part (20<=r<40) ----
        if (r < HN) {
            float a = qbs[r];
            #pragma unroll
            for (int i = 0; i < HN; ++i) a += qWs[r][i] * hd1[bloc][i];
            qs[bloc][r] = a;
        } else if (r < 2 * HN) {
            int k = r - HN;
            float a = cbbs[k];
            #pragma unroll
            for (int i = 0; i < HN; ++i) a += combWs[k][i] * hd1[bloc][i];
            combp[bloc][k] = a;
        }
        __syncthreads();
        // ---- scores: thread owns t = r (all 1024 threads) ----
        float sc = 0.0f;
        #pragma unroll
        for (int k = 0; k < HN; ++k)
            sc += qs[bloc][k] * el[r * 164 + k * 8 + bloc];
        {
            float m = sc;
            m = fmaxf(m, __shfl_xor(m, 8));
            m = fmaxf(m, __shfl_xor(m, 16));
            m = fmaxf(m, __shfl_xor(m, 32));
            if ((tid & 63) < 8) pm[wv][bloc] = m;
        }
        __syncthreads();
        if (tid < 8) {
            float m = pm[0][tid];
            #pragma unroll
            for (int w2 = 1; w2 < 16; ++w2) m = fmaxf(m, pm[w2][tid]);
            Ms[tid] = m;
        }
        __syncthreads();
        float ev = __expf(sc - Ms[bloc]);
        ssb[r * 9 + bloc] = ev;
        {
            float sm = ev;
            sm += __shfl_xor(sm, 8);
            sm += __shfl_xor(sm, 16);
            sm += __shfl_xor(sm, 32);
            if ((tid & 63) < 8) pm[wv][bloc] = sm;
        }
        __syncthreads();
        if (tid < 8) {
            float sm = pm[0][tid];
            #pragma unroll
            for (int w2 = 1; w2 < 16; ++w2) sm += pm[w2][tid];
            Sv[tid] = 1.0f / sm;
        }
        __syncthreads();
        // ---- attn write (coalesced remap) + context partials (4-way t) ----
        {
            int vb = tid >> 7, vt = tid & 127;
            out[(size_t)ATTN_OFF + (size_t)s * NB * NS + (size_t)(b0 + vb) * NS + vt]
                = ssb[vt * 9 + vb] * Sv[vb];
        }
        if (r < 80) {
            int ch = r / 20, k = r - 20 * ch;
            int t0 = ch * 32;
            float acc = 0.0f;
            for (int u = 0; u < 32; ++u)
                acc += ssb[(t0 + u) * 9 + bloc] * el[(t0 + u) * 164 + k * 8 + bloc];
            cxp[ch][k][bloc] = acc;
        }
        __syncthreads();
        // ---- comb += ctx part ----
        if (r < HN) {
            float a = combp[bloc][r];
            float inv = Sv[bloc];
            #pragma unroll
            for (int i = 0; i < HN; ++i) {
                float cx = (cxp[0][i][bloc] + cxp[1][i][bloc]
                          + cxp[2][i][bloc] + cxp[3][i][bloc]) * inv;
                a += combWs[r][HN + i] * cx;
            }
            combp[bloc][r] = a;
        }
        __syncthreads();
        // ---- logits: thread owns v = r; first-index argmax ----
        {
            float lg = outbs[r];
            #pragma unroll
            for (int k = 0; k < HN; ++k) lg += outWs[r][k] * combp[bloc][k];
            ssb[r * 9 + bloc] = lg;
            float bv = lg; int bi2 = r;
            #pragma unroll
            for (int d = 8; d <= 32; d <<= 1) {
                float ov = __shfl_xor(bv, d);
                int   oi = __shfl_xor(bi2, d);
                if (ov > bv || (ov == bv && oi < bi2)) { bv = ov; bi2 = oi; }
            }
            if ((tid & 63) < 8) { pm[wv][bloc] = bv; pix[wv][bloc] = bi2; }
        }
        __syncthreads();
        // ---- logits write (coalesced) + final argmax -> next token ----
        {
            int vb = tid >> 7, vt = tid & 127;
            out[(size_t)(b0 + vb) * (NDEC * NVOCAB) + s * NVOCAB + vt]
                = ssb[vt * 9 + vb];
        }
        if (tid < 8) {
            float bv = pm[0][tid]; int bi2 = pix[0][tid];
            #pragma unroll
            for (int w2 = 1; w2 < 16; ++w2) {
                float ov = pm[w2][tid]; int oi = pix[w2][tid];
                if (ov > bv || (ov == bv && oi < bi2)) { bv = ov; bi2 = oi; }
            }
            toks[tid] = bi2;
        }
        __syncthreads();
    }

    // ---- final hidden state [2][B][H] ----
    for (int idx = tid; idx < 8 * HN; idx += 1024) {
        int bb = idx & 7, k = idx >> 3;
        out[HID_OFF + (b0 + bb) * HN + k] = hd0[bb][k];
        out[HID_OFF + NB * HN + (b0 + bb) * HN + k] = hd1[bb][k];
    }
}

extern "C" void kernel_launch(void* const* d_in, const int* in_sizes, int n_in,
                              void* d_out, int out_size, void* d_ws, size_t ws_size,
                              hipStream_t stream)
{
    const float* x        = (const float*)d_in[0];
    const float* eWih0    = (const float*)d_in[1];
    const float* eWhh0    = (const float*)d_in[2];
    const float* ebih0    = (const float*)d_in[3];
    const float* ebhh0    = (const float*)d_in[4];
    const float* eWih1    = (const float*)d_in[5];
    const float* eWhh1    = (const float*)d_in[6];
    const float* ebih1    = (const float*)d_in[7];
    const float* ebhh1    = (const float*)d_in[8];
    const float* dWih0    = (const float*)d_in[9];
    const float* dWhh0    = (const float*)d_in[10];
    const float* dbih0    = (const float*)d_in[11];
    const float* dbhh0    = (const float*)d_in[12];
    const float* dWih1    = (const float*)d_in[13];
    const float* dWhh1    = (const float*)d_in[14];
    const float* dbih1    = (const float*)d_in[15];
    const float* dbhh1    = (const float*)d_in[16];
    const float* emb      = (const float*)d_in[17];
    const float* qW       = (const float*)d_in[18];
    const float* qb       = (const float*)d_in[19];
    const float* combW    = (const float*)d_in[20];
    const float* combb    = (const float*)d_in[21];
    const float* outW     = (const float*)d_in[22];
    const float* outb     = (const float*)d_in[23];

    // workspace: enc [NS][HN][NB] + hfin0 [NB][HN] + hfin1 [NB][HN]
    const size_t need = ((size_t)NS * HN * NB + 2 * (size_t)NB * HN) * sizeof(float);
    if (ws_size < need) return;

    float* ws  = (float*)d_ws;
    float* enc = ws;
    float* hf0 = ws + (size_t)NS * HN * NB;
    float* hf1 = hf0 + (size_t)NB * HN;

    enc_kernel<<<1024, 512, 0, stream>>>(x, eWih0, eWhh0, ebih0, ebhh0,
                                         eWih1, eWhh1, ebih1, ebhh1,
                                         enc, hf0, hf1);
    dec_kernel<<<1024, 1024, 0, stream>>>(dWih0, dWhh0, dbih0, dbhh0,
                                          dWih1, dWhh1, dbih1, dbhh1,
                                          emb, qW, qb, combW, combb, outW, outb,
                                          enc, hf0, hf1, (float*)d_out);
}

// Round 3
// 1003.130 us; speedup vs baseline: 1.8524x; 1.0888x over previous
//
#include <hip/hip_runtime.h>

// trajectory2seq: 2-layer GRU encoder (S=128) + attention decoder (6 steps)
// Round 4:
//   enc: explicit fmaf() chains (the a*b+c*d+... form blocked FMA fusion ->
//        ~2x VALU inflation seen in R2 counters); biases hoisted to regs;
//        output relaid batch-major enc[b][t][k] for the new decoder.
//   dec: REWRITTEN wave-per-batch-element. Each wave owns one b; the 128x20
//        enc tile lives in REGISTERS (2 t-rows/lane, staged once, reused all
//        6 steps); gates at lane=row with shfl redistribution; softmax /
//        context / argmax via full-wave shfl_xor butterflies; h/q/comb
//        broadcast via 80B wave-private LDS. No block-wide lockstep (5 cheap
//        4-wave syncs/step), ~1.3KB LDS/block -> occupancy VGPR-limited.
// ws layout: enc [8192][128][20] fp32 (batch-major) + hfin0 [8192][20].

#define HN 20
#define DIN 64
#define NVOCAB 128
#define NB 8192
#define NS 128
#define NDEC 6

#define HID_OFF (NB * NDEC * NVOCAB)      // 6291456
#define ATTN_OFF (HID_OFF + 2 * NB * HN)  // 6619136

__device__ __forceinline__ float sigf(float x) {
    return 1.0f / (1.0f + __expf(-x));
}

__global__ __launch_bounds__(512, 8)
void enc_kernel(const float* __restrict__ x,
                const float* __restrict__ Wih0, const float* __restrict__ Whh0,
                const float* __restrict__ bih0, const float* __restrict__ bhh0,
                const float* __restrict__ Wih1, const float* __restrict__ Whh1,
                const float* __restrict__ bih1, const float* __restrict__ bhh1,
                float* __restrict__ enc, float* __restrict__ hf0)
{
    // LDS = 16320 + 3*4800 + 2176 + 2*768 + 2*2560 = 39552 B -> 4 blocks/CU
    __shared__ __align__(16) float W0[60][68];   // Wih0 [60][64]
    __shared__ __align__(16) float U0[60][20];   // Whh0
    __shared__ __align__(16) float W1[60][20];   // Wih1
    __shared__ __align__(16) float U1[60][20];   // Whh1
    __shared__ __align__(16) float xs[8][68];    // x tile (single buffer)
    __shared__ __align__(16) float h0s[8][24];
    __shared__ __align__(16) float h1s[8][24];
    __shared__ float gA[80][8];                  // L0 gates(t):   2-way max
    __shared__ float gB[80][8];                  // L1 gates(t-1): 2-way max

    const int tid  = threadIdx.x;
    const int bloc = tid & 7;        // batch elem within block
    const int r    = tid >> 3;       // gate row 0..63
    const int sb   = tid >> 6;       // staging: batch lane 0..7 (wave-uniform)
    const int si   = tid & 63;       // staging: input feature 0..63
    const int bid  = (int)blockIdx.x;
    const int gblk = (bid & 7) * 128 + (bid >> 3);  // XCD-chunked, bijective
    const int b0   = gblk * 8;

    for (int idx = tid; idx < 60 * 64; idx += 512)
        W0[idx >> 6][idx & 63] = Wih0[idx];
    for (int idx = tid; idx < 60 * 20; idx += 512) {
        (&U0[0][0])[idx] = Whh0[idx];
        (&W1[0][0])[idx] = Wih1[idx];
        (&U1[0][0])[idx] = Whh1[idx];
    }
    // biases in registers (wave-uniform r -> scalar-ish, read once)
    float bi0r = 0.f, bh0r = 0.f, bi1r = 0.f, bh1r = 0.f;
    if (r < 60) {
        bi0r = bih0[r]; bh0r = bhh0[r];
        bi1r = bih1[r]; bh1r = bhh1[r];
    }
    for (int idx = tid; idx < 8 * 24; idx += 512) {
        (&h0s[0][0])[idx] = 0.0f;
        (&h1s[0][0])[idx] = 0.0f;
    }
    xs[sb][si] = x[(b0 + sb) * (NS * DIN) + si];   // t = 0
    __syncthreads();

    // software-pipelined: iter i computes gates0(t=i) and gates1(t=i-1)
    for (int i = 0; i <= NS; ++i) {
        float pf = 0.0f;
        const bool havepf = (i <= NS - 2);
        if (havepf)
            pf = x[((b0 + sb) * NS + i + 1) * DIN + si];

        // ---- phase G: both gate sets (read-only on xs/h0s/h1s) ----
        const bool g0 = (i < NS) && (r < 60);
        const bool g1 = (i >= 1) && (r < 60);
        if (g0) {
            float ax0 = bi0r, ax1 = 0.0f;
            #pragma unroll
            for (int q = 0; q < 16; q += 2) {
                float4 wv = *(const float4*)(&W0[r][4 * q]);
                float4 xv = *(const float4*)(&xs[bloc][4 * q]);
                ax0 = fmaf(wv.x, xv.x, ax0); ax0 = fmaf(wv.y, xv.y, ax0);
                ax0 = fmaf(wv.z, xv.z, ax0); ax0 = fmaf(wv.w, xv.w, ax0);
                float4 wu = *(const float4*)(&W0[r][4 * q + 4]);
                float4 xu = *(const float4*)(&xs[bloc][4 * q + 4]);
                ax1 = fmaf(wu.x, xu.x, ax1); ax1 = fmaf(wu.y, xu.y, ax1);
                ax1 = fmaf(wu.z, xu.z, ax1); ax1 = fmaf(wu.w, xu.w, ax1);
            }
            float ax = ax0 + ax1;
            float ah = bh0r;
            #pragma unroll
            for (int q = 0; q < 5; ++q) {
                float4 uv = *(const float4*)(&U0[r][4 * q]);
                float4 hv = *(const float4*)(&h0s[bloc][4 * q]);
                ah = fmaf(uv.x, hv.x, ah); ah = fmaf(uv.y, hv.y, ah);
                ah = fmaf(uv.z, hv.z, ah); ah = fmaf(uv.w, hv.w, ah);
            }
            if (r < 40) gA[r][bloc] = ax + ah;
            else { gA[r][bloc] = ax; gA[r + 20][bloc] = ah; }  // inn | hn
        }
        if (g1) {
            float bx = bi1r;
            #pragma unroll
            for (int q = 0; q < 5; ++q) {
                float4 wv = *(const float4*)(&W1[r][4 * q]);
                float4 hv = *(const float4*)(&h0s[bloc][4 * q]);
                bx = fmaf(wv.x, hv.x, bx); bx = fmaf(wv.y, hv.y, bx);
                bx = fmaf(wv.z, hv.z, bx); bx = fmaf(wv.w, hv.w, bx);
            }
            float bh = bh1r;
            #pragma unroll
            for (int q = 0; q < 5; ++q) {
                float4 uv = *(const float4*)(&U1[r][4 * q]);
                float4 hv = *(const float4*)(&h1s[bloc][4 * q]);
                bh = fmaf(uv.x, hv.x, bh); bh = fmaf(uv.y, hv.y, bh);
                bh = fmaf(uv.z, hv.z, bh); bh = fmaf(uv.w, hv.w, bh);
            }
            if (r < 40) gB[r][bloc] = bx + bh;
            else { gB[r][bloc] = bx; gB[r + 20][bloc] = bh; }
        }
        __syncthreads();

        // ---- phase U: write prefetched x; update h0(i) and h1(i-1) ----
        if (havepf) xs[sb][si] = pf;
        if (r < HN) {
            if (i < NS) {
                float rr = sigf(gA[r][bloc]);
                float z  = sigf(gA[20 + r][bloc]);
                float n  = tanhf(gA[40 + r][bloc] + rr * gA[60 + r][bloc]);
                float hnew = (1.0f - z) * n + z * h0s[bloc][r];
                h0s[bloc][r] = hnew;
                if (i == NS - 1) hf0[(b0 + bloc) * HN + r] = hnew;
            }
            if (i >= 1) {
                int t1 = i - 1;
                float rr = sigf(gB[r][bloc]);
                float z  = sigf(gB[20 + r][bloc]);
                float n  = tanhf(gB[40 + r][bloc] + rr * gB[60 + r][bloc]);
                float hnew = (1.0f - z) * n + z * h1s[bloc][r];
                h1s[bloc][r] = hnew;
                enc[(size_t)(b0 + bloc) * (NS * HN) + t1 * HN + r] = hnew; // [b][t][k]
            }
        }
        __syncthreads();
    }
}

// Decoder: 1 wave = 1 batch element. enc tile in registers (2 t-rows/lane).
__global__ __launch_bounds__(256)
void dec_kernel(const float* __restrict__ dWih0, const float* __restrict__ dWhh0,
                const float* __restrict__ dbih0, const float* __restrict__ dbhh0,
                const float* __restrict__ dWih1, const float* __restrict__ dWhh1,
                const float* __restrict__ dbih1, const float* __restrict__ dbhh1,
                const float* __restrict__ emb,  const float* __restrict__ qW,
                const float* __restrict__ qb,   const float* __restrict__ combW,
                const float* __restrict__ combb, const float* __restrict__ outW,
                const float* __restrict__ outb,
                const float* __restrict__ enc, const float* __restrict__ hf0,
                float* __restrict__ out)
{
    __shared__ __align__(16) float hb0[4][20];   // wave-private broadcasts
    __shared__ __align__(16) float hb1[4][20];
    __shared__ __align__(16) float qsh[4][20];
    __shared__ __align__(16) float csh[4][20];

    const int tid  = threadIdx.x;
    const int l    = tid & 63;
    const int wv   = tid >> 6;
    const int bid  = (int)blockIdx.x;
    const int gblk = (bid & 7) * 256 + (bid >> 3);  // 2048 = 8*256, bijective
    const int b    = gblk * 4 + wv;

    // ---- stage enc tile into registers: lane l holds t=l and t=64+l ----
    float e0[20], e1[20];
    const float* src = enc + (size_t)b * (NS * HN);
    #pragma unroll
    for (int q = 0; q < 5; ++q) {
        float4 v = *(const float4*)(src + l * HN + 4 * q);
        e0[4*q+0] = v.x; e0[4*q+1] = v.y; e0[4*q+2] = v.z; e0[4*q+3] = v.w;
        float4 u = *(const float4*)(src + (64 + l) * HN + 4 * q);
        e1[4*q+0] = u.x; e1[4*q+1] = u.y; e1[4*q+2] = u.z; e1[4*q+3] = u.w;
    }
    float h0v = 0.0f, h1v = 0.0f;
    if (l < HN) {
        h0v = hf0[b * HN + l];
        h1v = src[127 * HN + l];      // h1 final = enc[b][127][:]
        hb0[wv][l] = h0v;
        hb1[wv][l] = h1v;
    }
    int tok = 0;
    __syncthreads();

    for (int s = 0; s < NDEC; ++s) {
        const float* ep = emb + tok * HN;   // tok uniform (readfirstlane'd)

        // ---- GRU L0: lane owns gate row l (l<60) ----
        float g = 0.0f, axn = 0.0f, ahn = 0.0f;
        if (l < 60) {
            const float* wi = dWih0 + l * HN;
            const float* wh = dWhh0 + l * HN;
            float ax = dbih0[l], ah = dbhh0[l];
            #pragma unroll
            for (int q = 0; q < 5; ++q) {
                float4 w4 = *(const float4*)(wi + 4 * q);
                ax = fmaf(w4.x, ep[4*q+0], ax); ax = fmaf(w4.y, ep[4*q+1], ax);
                ax = fmaf(w4.z, ep[4*q+2], ax); ax = fmaf(w4.w, ep[4*q+3], ax);
                float4 u4 = *(const float4*)(wh + 4 * q);
                float4 h4 = *(const float4*)(&hb0[wv][4 * q]);
                ah = fmaf(u4.x, h4.x, ah); ah = fmaf(u4.y, h4.y, ah);
                ah = fmaf(u4.z, h4.z, ah); ah = fmaf(u4.w, h4.w, ah);
            }
            g = ax + ah; axn = ax; ahn = ah;
        }
        // redistribute: lane k<20 needs rows k (own), 20+k, 40+k
        float zg  = __shfl(g,   l + 20);
        float inn = __shfl(axn, l + 40);
        float hnn = __shfl(ahn, l + 40);
        if (l < HN) {
            float rr = sigf(g);
            float zz = sigf(zg);
            float nn = tanhf(inn + rr * hnn);
            h0v = (1.0f - zz) * nn + zz * h0v;
            hb0[wv][l] = h0v;
        }
        __syncthreads();

        // ---- GRU L1 ----
        g = 0.0f; axn = 0.0f; ahn = 0.0f;
        if (l < 60) {
            const float* wi = dWih1 + l * HN;
            const float* wh = dWhh1 + l * HN;
            float ax = dbih1[l], ah = dbhh1[l];
            #pragma unroll
            for (int q = 0; q < 5; ++q) {
                float4 w4 = *(const float4*)(wi + 4 * q);
                float4 h4 = *(const float4*)(&hb0[wv][4 * q]);
                ax = fmaf(w4.x, h4.x, ax); ax = fmaf(w4.y, h4.y, ax);
                ax = fmaf(w4.z, h4.z, ax); ax = fmaf(w4.w, h4.w, ax);
                float4 u4 = *(const float4*)(wh + 4 * q);
                float4 g4 = *(const float4*)(&hb1[wv][4 * q]);
                ah = fmaf(u4.x, g4.x, ah); ah = fmaf(u4.y, g4.y, ah);
                ah = fmaf(u4.z, g4.z, ah); ah = fmaf(u4.w, g4.w, ah);
            }
            g = ax + ah; axn = ax; ahn = ah;
        }
        zg  = __shfl(g,   l + 20);
        inn = __shfl(axn, l + 40);
        hnn = __shfl(ahn, l + 40);
        if (l < HN) {
            float rr = sigf(g);
            float zz = sigf(zg);
            float nn = tanhf(inn + rr * hnn);
            h1v = (1.0f - zz) * nn + zz * h1v;
            hb1[wv][l] = h1v;
        }
        __syncthreads();

        // ---- query (lanes<20) + comb buf-part (lanes 20..39) ----
        float cbv = 0.0f;
        if (l < HN) {
            float qv = qb[l];
            const float* qr = qW + l * HN;
            #pragma unroll
            for (int q = 0; q < 5; ++q) {
                float4 w4 = *(const float4*)(qr + 4 * q);
                float4 h4 = *(const float4*)(&hb1[wv][4 * q]);
                qv = fmaf(w4.x, h4.x, qv); qv = fmaf(w4.y, h4.y, qv);
                qv = fmaf(w4.z, h4.z, qv); qv = fmaf(w4.w, h4.w, qv);
            }
            qsh[wv][l] = qv;
        } else if (l < 2 * HN) {
            int k2 = l - HN;
            cbv = combb[k2];
            const float* cr = combW + k2 * 2 * HN;
            #pragma unroll
            for (int q = 0; q < 5; ++q) {
                float4 w4 = *(const float4*)(cr + 4 * q);
                float4 h4 = *(const float4*)(&hb1[wv][4 * q]);
                cbv = fmaf(w4.x, h4.x, cbv); cbv = fmaf(w4.y, h4.y, cbv);
                cbv = fmaf(w4.z, h4.z, cbv); cbv = fmaf(w4.w, h4.w, cbv);
            }
        }
        __syncthreads();

        // ---- scores (lane owns t=l, t=64+l; e-tile in regs) ----
        float s0 = 0.0f, s1 = 0.0f;
        #pragma unroll
        for (int k = 0; k < HN; ++k) {
            float qk = qsh[wv][k];
            s0 = fmaf(qk, e0[k], s0);
            s1 = fmaf(qk, e1[k], s1);
        }
        float m = fmaxf(s0, s1);
        #pragma unroll
        for (int d = 1; d < 64; d <<= 1) m = fmaxf(m, __shfl_xor(m, d));
        float x0 = __expf(s0 - m), x1 = __expf(s1 - m);
        float sm = x0 + x1;
        #pragma unroll
        for (int d = 1; d < 64; d <<= 1) sm += __shfl_xor(sm, d);
        float inv = 1.0f / sm;
        float w0 = x0 * inv, w1 = x1 * inv;
        {
            size_t abase = (size_t)ATTN_OFF + (size_t)s * NB * NS + (size_t)b * NS;
            out[abase + l]      = w0;
            out[abase + 64 + l] = w1;
        }

        // ---- context: per-lane partials + elementwise butterfly ----
        float cx[20];
        #pragma unroll
        for (int k = 0; k < HN; ++k) cx[k] = fmaf(w1, e1[k], w0 * e0[k]);
        #pragma unroll
        for (int d = 1; d < 64; d <<= 1) {
            #pragma unroll
            for (int k = 0; k < HN; ++k) cx[k] += __shfl_xor(cx[k], d);
        }
        // every lane now holds full ctx[0..19]

        // ---- comb finish (lanes<20) ----
        float cpre = __shfl(cbv, l + 20);
        if (l < HN) {
            float cv = cpre;
            const float* cr = combW + l * 2 * HN + HN;
            #pragma unroll
            for (int q = 0; q < 5; ++q) {
                float4 w4 = *(const float4*)(cr + 4 * q);
                cv = fmaf(w4.x, cx[4*q+0], cv); cv = fmaf(w4.y, cx[4*q+1], cv);
                cv = fmaf(w4.z, cx[4*q+2], cv); cv = fmaf(w4.w, cx[4*q+3], cv);
            }
            csh[wv][l] = cv;
        }
        __syncthreads();

        // ---- logits (lane owns v=l, v=64+l) + first-index argmax ----
        float lg0 = outb[l], lg1 = outb[64 + l];
        {
            const float* o0 = outW + l * HN;
            const float* o1 = outW + (64 + l) * HN;
            #pragma unroll
            for (int q = 0; q < 5; ++q) {
                float4 a4 = *(const float4*)(o0 + 4 * q);
                float4 b4 = *(const float4*)(o1 + 4 * q);
                float4 c4 = *(const float4*)(&csh[wv][4 * q]);
                lg0 = fmaf(a4.x, c4.x, lg0); lg0 = fmaf(a4.y, c4.y, lg0);
                lg0 = fmaf(a4.z, c4.z, lg0); lg0 = fmaf(a4.w, c4.w, lg0);
                lg1 = fmaf(b4.x, c4.x, lg1); lg1 = fmaf(b4.y, c4.y, lg1);
                lg1 = fmaf(b4.z, c4.z, lg1); lg1 = fmaf(b4.w, c4.w, lg1);
            }
        }
        {
            size_t lbase = (size_t)b * (NDEC * NVOCAB) + (size_t)s * NVOCAB;
            out[lbase + l]      = lg0;
            out[lbase + 64 + l] = lg1;
        }
        float bv = lg0; int bi2 = l;
        if (lg1 > bv) { bv = lg1; bi2 = 64 + l; }
        #pragma unroll
        for (int d = 1; d < 64; d <<= 1) {
            float ov = __shfl_xor(bv, d);
            int   oi = __shfl_xor(bi2, d);
            if (ov > bv || (ov == bv && oi < bi2)) { bv = ov; bi2 = oi; }
        }
        tok = __builtin_amdgcn_readfirstlane(bi2);
        __syncthreads();
    }

    // ---- final hidden state [2][B][H] ----
    if (l < HN) {
        out[HID_OFF + (size_t)b * HN + l]           = h0v;
        out[HID_OFF + NB * HN + (size_t)b * HN + l] = h1v;
    }
}

extern "C" void kernel_launch(void* const* d_in, const int* in_sizes, int n_in,
                              void* d_out, int out_size, void* d_ws, size_t ws_size,
                              hipStream_t stream)
{
    const float* x        = (const float*)d_in[0];
    const float* eWih0    = (const float*)d_in[1];
    const float* eWhh0    = (const float*)d_in[2];
    const float* ebih0    = (const float*)d_in[3];
    const float* ebhh0    = (const float*)d_in[4];
    const float* eWih1    = (const float*)d_in[5];
    const float* eWhh1    = (const float*)d_in[6];
    const float* ebih1    = (const float*)d_in[7];
    const float* ebhh1    = (const float*)d_in[8];
    const float* dWih0    = (const float*)d_in[9];
    const float* dWhh0    = (const float*)d_in[10];
    const float* dbih0    = (const float*)d_in[11];
    const float* dbhh0    = (const float*)d_in[12];
    const float* dWih1    = (const float*)d_in[13];
    const float* dWhh1    = (const float*)d_in[14];
    const float* dbih1    = (const float*)d_in[15];
    const float* dbhh1    = (const float*)d_in[16];
    const float* emb      = (const float*)d_in[17];
    const float* qW       = (const float*)d_in[18];
    const float* qb       = (const float*)d_in[19];
    const float* combW    = (const float*)d_in[20];
    const float* combb    = (const float*)d_in[21];
    const float* outW     = (const float*)d_in[22];
    const float* outb     = (const float*)d_in[23];

    // workspace: enc [NB][NS][HN] + hfin0 [NB][HN]
    const size_t need = ((size_t)NB * NS * HN + (size_t)NB * HN) * sizeof(float);
    if (ws_size < need) return;

    float* ws  = (float*)d_ws;
    float* enc = ws;
    float* hf0 = ws + (size_t)NB * NS * HN;

    enc_kernel<<<1024, 512, 0, stream>>>(x, eWih0, eWhh0, ebih0, ebhh0,
                                         eWih1, eWhh1, ebih1, ebhh1,
                                         enc, hf0);
    dec_kernel<<<2048, 256, 0, stream>>>(dWih0, dWhh0, dbih0, dbhh0,
                                         dWih1, dWhh1, dbih1, dbhh1,
                                         emb, qW, qb, combW, combb, outW, outb,
                                         enc, hf0, (float*)d_out);
}